// Round 2
// baseline (231.650 us; speedup 1.0000x reference)
//
#include <hip/hip_runtime.h>
#include <hip/hip_bf16.h>

typedef __bf16 bf16x8 __attribute__((ext_vector_type(8)));
typedef float  f32x4  __attribute__((ext_vector_type(4)));

#define B_  512
#define DX_ 128
#define H_  512

// ---------------------------------------------------------------------------
// pack: bf16-convert x,y,W1,W2 into MFMA-fragment-packed layouts.
//   PA[mt][ks][lane][8]  : A-fragments (row = mt*16 + lane%16, k = ks*32 + (lane/16)*8 + j)
//   PW[ks][nt][lane][8]  : B-fragments (col = nt*16 + lane%16, same k map)
// Identical k-map on A and B => dot-product invariant to HW internal k order.
// ---------------------------------------------------------------------------
__global__ __launch_bounds__(256) void pack_kernel(
    const float* __restrict__ x, const float* __restrict__ y,
    const float* __restrict__ W1, const float* __restrict__ W2,
    __bf16* __restrict__ PAx, __bf16* __restrict__ PAy,
    __bf16* __restrict__ PW1x, __bf16* __restrict__ PW1y,
    __bf16* __restrict__ PW2)
{
    int gid = blockIdx.x * 256 + threadIdx.x;
    if (gid < 16384) {
        const float* src = (gid < 8192) ? x : y;
        __bf16* dst = (gid < 8192) ? PAx : PAy;
        int u = gid & 8191;
        int mt = u >> 8, ks = (u >> 6) & 3, l = u & 63;
        int row = mt * 16 + (l & 15);
        int k = ks * 32 + ((l >> 4) << 3);
        const float* p = src + row * DX_ + k;
        bf16x8 v;
        #pragma unroll
        for (int j = 0; j < 8; ++j) v[j] = (__bf16)p[j];
        *(bf16x8*)(dst + u * 8) = v;
    } else if (gid < 32768) {
        int u = gid - 16384;
        int which = u >> 13;
        u &= 8191;
        int ks = u >> 11, nt = (u >> 6) & 31, l = u & 63;
        int k = ks * 32 + ((l >> 4) << 3);
        int col = nt * 16 + (l & 15);
        const float* p = W1 + (which * 128 + k) * H_ + col;
        __bf16* dst = which ? PW1y : PW1x;
        bf16x8 v;
        #pragma unroll
        for (int j = 0; j < 8; ++j) v[j] = (__bf16)p[j * H_];
        *(bf16x8*)(dst + u * 8) = v;
    } else {
        int u = gid - 32768;                     // 0..32767 -> ks 0..15
        int ks = u >> 11, nt = (u >> 6) & 31, l = u & 63;
        int k = ks * 32 + ((l >> 4) << 3);
        int col = nt * 16 + (l & 15);
        const float* p = W2 + k * H_ + col;
        bf16x8 v;
        #pragma unroll
        for (int j = 0; j < 8; ++j) v[j] = (__bf16)p[j * H_];
        *(bf16x8*)(PW2 + u * 8) = v;
    }
}

// ---------------------------------------------------------------------------
// hxy: hx = x@W1x ; hyb = y@W1y + b1   (M=512, K=128, N=512, f32 out)
// block = 256 thr (4 waves, 1m x 4n), tile 64x128, per-wave 64x32.
// ---------------------------------------------------------------------------
__global__ __launch_bounds__(256) void hxy_kernel(
    const __bf16* __restrict__ PAx, const __bf16* __restrict__ PAy,
    const __bf16* __restrict__ PW1x, const __bf16* __restrict__ PW1y,
    const float* __restrict__ b1,
    float* __restrict__ hx, float* __restrict__ hyb)
{
    int task = blockIdx.z;
    const __bf16* PA = task ? PAy : PAx;
    const __bf16* PW = task ? PW1y : PW1x;
    float* outp = task ? hyb : hx;
    int bm = blockIdx.y;   // 0..7  (64-row tiles)
    int bn = blockIdx.x;   // 0..3  (128-col tiles)
    int tid = threadIdx.x;
    int w = tid >> 6, lane = tid & 63;

    f32x4 acc[4][2] = {};
    #pragma unroll
    for (int ks = 0; ks < 4; ++ks) {
        bf16x8 af[4];
        #pragma unroll
        for (int mt = 0; mt < 4; ++mt)
            af[mt] = *(const bf16x8*)(PA + (((bm * 4 + mt) * 4 + ks) * 64 + lane) * 8);
        #pragma unroll
        for (int nt = 0; nt < 2; ++nt) {
            bf16x8 bf = *(const bf16x8*)(PW + ((ks * 32 + bn * 8 + w * 2 + nt) * 64 + lane) * 8);
            #pragma unroll
            for (int mt = 0; mt < 4; ++mt)
                acc[mt][nt] = __builtin_amdgcn_mfma_f32_16x16x32_bf16(af[mt], bf, acc[mt][nt], 0, 0, 0);
        }
    }
    #pragma unroll
    for (int nt = 0; nt < 2; ++nt) {
        int col = bn * 128 + (w * 2 + nt) * 16 + (lane & 15);
        float badd = task ? b1[col] : 0.f;
        #pragma unroll
        for (int mt = 0; mt < 4; ++mt) {
            #pragma unroll
            for (int r = 0; r < 4; ++r) {
                int row = bm * 64 + mt * 16 + ((lane >> 4) << 2) + r;   // D: row=(l>>4)*4+reg
                outp[row * H_ + col] = acc[mt][nt][r] + badd;
            }
        }
    }
}

// ---------------------------------------------------------------------------
// main: per block, a 128-pair-row (16 i x 8 j) x N=512 tile of the virtual
// (B*B x H) @ (H x H) GEMM; h1 generated on the fly into swizzled LDS,
// W2 fragments streamed from L2 (packed), epilogue fuses relu/b2/W3/b3.
// 512 thr = 8 waves (2m x 4n); wave = 64 rows x 128 cols; 128 accum VGPR.
// ---------------------------------------------------------------------------
__global__ __launch_bounds__(512, 2) void critic_kernel(
    const float* __restrict__ hx, const float* __restrict__ hyb,
    const __bf16* __restrict__ PW2,
    const float* __restrict__ b2, const float* __restrict__ W3,
    const float* __restrict__ b3, float* __restrict__ out)
{
    __shared__ float hx_s[16 * 516];               // +4 pad: kill 8-way conflicts
    __shared__ float hy_s[8 * 516];
    __shared__ __align__(16) char h1_s[128 * 64];  // [128 rows][32 k] bf16, XOR-swizzled
    __shared__ float sc_s[128];

    int tid = threadIdx.x;
    int lane = tid & 63, wid = tid >> 6;
    int mw = wid >> 2, nw = wid & 3;
    int bj = blockIdx.x, bi = blockIdx.y;

    // stage hx (16 rows) / hyb (8 rows) into LDS, padded stride 516
    for (int idx = tid; idx < 16 * 128; idx += 512) {
        int r = idx >> 7, c4 = (idx & 127) << 2;
        *(float4*)&hx_s[r * 516 + c4] = *(const float4*)&hx[(bi * 16 + r) * H_ + c4];
    }
    for (int idx = tid; idx < 8 * 128; idx += 512) {
        int r = idx >> 7, c4 = (idx & 127) << 2;
        *(float4*)&hy_s[r * 516 + c4] = *(const float4*)&hyb[(bj * 8 + r) * H_ + c4];
    }

    // h1 generation: thread -> (row=tid/4, k-octet q=tid&3); swizzle 16B slots
    int grow = tid >> 2, q = tid & 3;
    const float* px = &hx_s[(grow >> 3) * 516 + q * 8];
    const float* py = &hy_s[(grow & 7) * 516 + q * 8];
    char* wptr = h1_s + grow * 64 + ((q << 4) ^ ((grow & 3) << 4));

    // A-fragment read addresses (same swizzle)
    int aoff[4];
    #pragma unroll
    for (int mt = 0; mt < 4; ++mt) {
        int arow = mw * 64 + mt * 16 + (lane & 15);
        int slot = (lane >> 4) ^ (arow & 3);
        aoff[mt] = arow * 64 + (slot << 4);
    }

    f32x4 acc[4][8] = {};

    for (int ks = 0; ks < 16; ++ks) {
        __syncthreads();                            // readers of prev chunk done
        {
            const float4 a0 = *(const float4*)(px + ks * 32);
            const float4 a1 = *(const float4*)(px + ks * 32 + 4);
            const float4 c0 = *(const float4*)(py + ks * 32);
            const float4 c1 = *(const float4*)(py + ks * 32 + 4);
            bf16x8 hv;
            hv[0] = (__bf16)fmaxf(a0.x + c0.x, 0.f);
            hv[1] = (__bf16)fmaxf(a0.y + c0.y, 0.f);
            hv[2] = (__bf16)fmaxf(a0.z + c0.z, 0.f);
            hv[3] = (__bf16)fmaxf(a0.w + c0.w, 0.f);
            hv[4] = (__bf16)fmaxf(a1.x + c1.x, 0.f);
            hv[5] = (__bf16)fmaxf(a1.y + c1.y, 0.f);
            hv[6] = (__bf16)fmaxf(a1.z + c1.z, 0.f);
            hv[7] = (__bf16)fmaxf(a1.w + c1.w, 0.f);
            *(bf16x8*)wptr = hv;
        }
        __syncthreads();
        bf16x8 af[4];
        #pragma unroll
        for (int mt = 0; mt < 4; ++mt)
            af[mt] = *(const bf16x8*)(h1_s + aoff[mt]);
        const __bf16* pb = PW2 + ((ks * 32 + nw * 8) * 64 + lane) * 8;
        #pragma unroll
        for (int nt = 0; nt < 8; ++nt) {
            bf16x8 bf = *(const bf16x8*)(pb + nt * 64 * 8);
            #pragma unroll
            for (int mt = 0; mt < 4; ++mt)
                acc[mt][nt] = __builtin_amdgcn_mfma_f32_16x16x32_bf16(af[mt], bf, acc[mt][nt], 0, 0, 0);
        }
    }

    // epilogue: score[row] = b3 + sum_col relu(acc + b2[col]) * W3[col]
    __syncthreads();
    if (tid < 128) sc_s[tid] = 0.f;
    __syncthreads();

    float b2v[8], w3v[8];
    #pragma unroll
    for (int nt = 0; nt < 8; ++nt) {
        int col = nw * 128 + nt * 16 + (lane & 15);
        b2v[nt] = b2[col];
        w3v[nt] = W3[col];
    }
    #pragma unroll
    for (int mt = 0; mt < 4; ++mt) {
        #pragma unroll
        for (int r = 0; r < 4; ++r) {
            float s = 0.f;
            #pragma unroll
            for (int nt = 0; nt < 8; ++nt) {
                float h2 = acc[mt][nt][r] + b2v[nt];
                h2 = fmaxf(h2, 0.f);
                s += h2 * w3v[nt];
            }
            s += __shfl_xor(s, 1);
            s += __shfl_xor(s, 2);
            s += __shfl_xor(s, 4);
            s += __shfl_xor(s, 8);
            if ((lane & 15) == 0)
                atomicAdd(&sc_s[mw * 64 + mt * 16 + ((lane >> 4) << 2) + r], s);
        }
    }
    __syncthreads();
    if (tid < 128) {
        int i = bi * 16 + (tid >> 3);
        int j = bj * 8 + (tid & 7);
        out[i * B_ + j] = sc_s[tid] + b3[0];
    }
}

// ---------------------------------------------------------------------------
extern "C" void kernel_launch(void* const* d_in, const int* in_sizes, int n_in,
                              void* d_out, int out_size, void* d_ws, size_t ws_size,
                              hipStream_t stream)
{
    const float* x  = (const float*)d_in[0];
    const float* y  = (const float*)d_in[1];
    const float* W1 = (const float*)d_in[2];
    const float* b1 = (const float*)d_in[3];
    const float* W2 = (const float*)d_in[4];
    const float* b2 = (const float*)d_in[5];
    const float* W3 = (const float*)d_in[6];
    const float* b3 = (const float*)d_in[7];
    float* out = (float*)d_out;

    char* ws = (char*)d_ws;
    float*  hx   = (float*)(ws);                   // 1 MB
    float*  hyb  = (float*)(ws + 1048576);         // 1 MB
    __bf16* PW2  = (__bf16*)(ws + 2097152);        // 512 KB
    __bf16* PAx  = (__bf16*)(ws + 2621440);        // 128 KB
    __bf16* PAy  = (__bf16*)(ws + 2752512);        // 128 KB
    __bf16* PW1x = (__bf16*)(ws + 2883584);        // 128 KB
    __bf16* PW1y = (__bf16*)(ws + 3014656);        // 128 KB  (end: 3 MB)

    hipLaunchKernelGGL(pack_kernel, dim3(256), dim3(256), 0, stream,
                       x, y, W1, W2, PAx, PAy, PW1x, PW1y, PW2);
    hipLaunchKernelGGL(hxy_kernel, dim3(4, 8, 2), dim3(256), 0, stream,
                       PAx, PAy, PW1x, PW1y, b1, hx, hyb);
    hipLaunchKernelGGL(critic_kernel, dim3(64, 32), dim3(512), 0, stream,
                       hx, hyb, PW2, b2, W3, b3, out);
}